// Round 2
// baseline (620.175 us; speedup 1.0000x reference)
//
#include <hip/hip_runtime.h>
#include <hip/hip_bf16.h>
#include <stdint.h>

#define D 128

typedef __attribute__((ext_vector_type(8))) short short8;
typedef __attribute__((ext_vector_type(4))) float f32x4;

__device__ inline float bf16lo(uint32_t u){ return __uint_as_float(u << 16); }
__device__ inline float bf16hi(uint32_t u){ return __uint_as_float(u & 0xffff0000u); }
__device__ inline unsigned short f2bf(float f){
    union { __hip_bfloat16 h; unsigned short u; } cvt;
    cvt.h = __float2bfloat16(f);
    return cvt.u;
}

// ---------- input fp32 -> bf16 ----------
__global__ void cvt_f32_bf16(const float* __restrict__ x, unsigned short* __restrict__ xb, int n8){
    int i = blockIdx.x * blockDim.x + threadIdx.x;
    if (i >= n8) return;
    const float4* p = reinterpret_cast<const float4*>(x) + (size_t)i * 2;
    float4 a = p[0], b = p[1];
    uint4 o;
    o.x = (uint32_t)f2bf(a.x) | ((uint32_t)f2bf(a.y) << 16);
    o.y = (uint32_t)f2bf(a.z) | ((uint32_t)f2bf(a.w) << 16);
    o.z = (uint32_t)f2bf(b.x) | ((uint32_t)f2bf(b.y) << 16);
    o.w = (uint32_t)f2bf(b.z) | ((uint32_t)f2bf(b.w) << 16);
    reinterpret_cast<uint4*>(xb)[i] = o;
}

// ---------- binned CSR build ----------
// bucket = dst >> 5 (32 nodes per bucket)
__global__ void count_bkt(const int* __restrict__ dst, int* __restrict__ cnt, int E){
    int e = blockIdx.x * 256 + threadIdx.x;
    if (e < E) atomicAdd(&cnt[dst[e] >> 5], 1);
}

// single-block exclusive scan of bucket counts -> bktbase (and a working copy bktfill)
__global__ void scan_bkt(const int* __restrict__ cnt, int* __restrict__ base,
                         int* __restrict__ bfill, int nb, int E){
    __shared__ int s[256];
    __shared__ int carry;
    int t = threadIdx.x;
    if (t == 0) carry = 0;
    __syncthreads();
    for (int start = 0; start < nb; start += 256){
        int i = start + t;
        int v = (i < nb) ? cnt[i] : 0;
        s[t] = v;
        __syncthreads();
        for (int o = 1; o < 256; o <<= 1){
            int x = (t >= o) ? s[t - o] : 0;
            __syncthreads();
            s[t] += x;
            __syncthreads();
        }
        int excl = carry + s[t] - v;
        if (i < nb){ base[i] = excl; bfill[i] = excl; }
        __syncthreads();
        if (t == 255) carry += s[255];
        __syncthreads();
    }
    if (t == 0) base[nb] = E;
}

// append (src,dst) pairs into bucket-ordered binbuf (dense, sequential within bucket)
__global__ void bin_edges(const int* __restrict__ src, const int* __restrict__ dst,
                          int* __restrict__ bfill, uint2* __restrict__ binbuf, int E){
    int e = blockIdx.x * 256 + threadIdx.x;
    if (e < E){
        int d = dst[e];
        int pos = atomicAdd(&bfill[d >> 5], 1);
        binbuf[pos] = make_uint2((unsigned)src[e], (unsigned)d);
    }
}

// one block per bucket: local histogram -> roff, then local scatter into csr (~2KB region)
__global__ void fill_bucket(const uint2* __restrict__ binbuf, const int* __restrict__ bktbase,
                            int* __restrict__ roff, int* __restrict__ csr, int n, int nb){
    __shared__ int hist[32];
    __shared__ int hbase[32];
    int b = blockIdx.x;
    int t = threadIdx.x;
    int e0 = bktbase[b], e1 = bktbase[b + 1];
    int v0 = b << 5;
    if (t < 32) hist[t] = 0;
    __syncthreads();
    for (int e = e0 + t; e < e1; e += 256){
        uint2 p = binbuf[e];
        atomicAdd(&hist[(int)p.y - v0], 1);
    }
    __syncthreads();
    if (t == 0){
        int s = e0;
        #pragma unroll
        for (int i = 0; i < 32; i++){ hbase[i] = s; s += hist[i]; hist[i] = 0; }
    }
    __syncthreads();
    if (t < 32 && v0 + t < n) roff[v0 + t] = hbase[t];
    if (b == nb - 1 && t == 0) roff[n] = e1;
    for (int e = e0 + t; e < e1; e += 256){
        uint2 p = binbuf[e];
        int loc = (int)p.y - v0;
        int pos = hbase[loc] + atomicAdd(&hist[loc], 1);
        csr[pos] = (int)p.x;
    }
}

// ---------- weight pre-transpose: WT[j][k] = bf16(Wcat[k][j]) ----------
__global__ void wt_prep(const float* __restrict__ Wl, const float* __restrict__ Wr,
                        unsigned short* __restrict__ WT, int dout){
    int idx = blockIdx.x * 256 + threadIdx.x;
    if (idx >= dout * 256) return;
    int k = idx & 255, j = idx >> 8;
    float w = (k < 128) ? Wl[k * dout + j] : Wr[(k - 128) * dout + j];
    WT[j * 256 + k] = f2bf(w);
}

// ---------- fused layer: aggregate(64 rows)->LDS, then [agg|h] @ [Wl;Wr] + b ----------
template<int DOUT, bool RELU, bool OUTBF>
__global__ __launch_bounds__(256, 2) void sage_layer(
    const unsigned short* __restrict__ hb,
    const int* __restrict__ roff, const int* __restrict__ csr,
    const unsigned short* __restrict__ WT, const float* __restrict__ bias,
    unsigned short* __restrict__ outb, float* __restrict__ outf, int n)
{
    constexpr int CF = DOUT / 64;
    __shared__ __align__(16) unsigned short As[64][136];   // pitch 136 -> conflict-free frag reads
    int tid = threadIdx.x;
    int lane = tid & 63, wave = tid >> 6;
    int rbase = blockIdx.x * 64;
    int lrow = lane & 15, lk = (lane >> 4) * 8;
    int colbase = wave * 16 * CF;

    // B fragments in registers (weights are L2-resident, reused by all blocks)
    short8 bfr[8][CF];
    #pragma unroll
    for (int kk = 0; kk < 8; kk++)
        #pragma unroll
        for (int cf = 0; cf < CF; cf++)
            bfr[kk][cf] = *reinterpret_cast<const short8*>(
                WT + (size_t)(colbase + cf * 16 + lrow) * 256 + kk * 32 + lk);

    // ---- phase 1: mean-aggregate 64 rows into LDS (quarter-wave per node)
    int grp = tid >> 4, li = tid & 15;
    for (int p = 0; p < 4; p++){
        int row = p * 16 + grp;
        int v = rbase + row;
        float acc[8] = {0.f,0.f,0.f,0.f,0.f,0.f,0.f,0.f};
        int dcount = 0;
        if (v < n){
            int s0 = roff[v], s1 = roff[v + 1];
            dcount = s1 - s0;
            int e = s0;
            for (; e + 1 < s1; e += 2){
                int sA = csr[e], sB = csr[e + 1];
                uint4 qa = *reinterpret_cast<const uint4*>(hb + (size_t)sA * D + li * 8);
                uint4 qb = *reinterpret_cast<const uint4*>(hb + (size_t)sB * D + li * 8);
                acc[0] += bf16lo(qa.x); acc[1] += bf16hi(qa.x);
                acc[2] += bf16lo(qa.y); acc[3] += bf16hi(qa.y);
                acc[4] += bf16lo(qa.z); acc[5] += bf16hi(qa.z);
                acc[6] += bf16lo(qa.w); acc[7] += bf16hi(qa.w);
                acc[0] += bf16lo(qb.x); acc[1] += bf16hi(qb.x);
                acc[2] += bf16lo(qb.y); acc[3] += bf16hi(qb.y);
                acc[4] += bf16lo(qb.z); acc[5] += bf16hi(qb.z);
                acc[6] += bf16lo(qb.w); acc[7] += bf16hi(qb.w);
            }
            if (e < s1){
                int sA = csr[e];
                uint4 qa = *reinterpret_cast<const uint4*>(hb + (size_t)sA * D + li * 8);
                acc[0] += bf16lo(qa.x); acc[1] += bf16hi(qa.x);
                acc[2] += bf16lo(qa.y); acc[3] += bf16hi(qa.y);
                acc[4] += bf16lo(qa.z); acc[5] += bf16hi(qa.z);
                acc[6] += bf16lo(qa.w); acc[7] += bf16hi(qa.w);
            }
        }
        float inv = (dcount > 0) ? 1.0f / (float)dcount : 0.0f;
        uint4 o;
        o.x = (uint32_t)f2bf(acc[0]*inv) | ((uint32_t)f2bf(acc[1]*inv) << 16);
        o.y = (uint32_t)f2bf(acc[2]*inv) | ((uint32_t)f2bf(acc[3]*inv) << 16);
        o.z = (uint32_t)f2bf(acc[4]*inv) | ((uint32_t)f2bf(acc[5]*inv) << 16);
        o.w = (uint32_t)f2bf(acc[6]*inv) | ((uint32_t)f2bf(acc[7]*inv) << 16);
        *reinterpret_cast<uint4*>(&As[row][li * 8]) = o;
    }
    __syncthreads();

    // ---- phase 2: MFMA GEMM
    f32x4 acc[4][CF];
    #pragma unroll
    for (int fr = 0; fr < 4; fr++)
        #pragma unroll
        for (int cf = 0; cf < CF; cf++)
            acc[fr][cf] = (f32x4){0.f, 0.f, 0.f, 0.f};

    int r[4];
    #pragma unroll
    for (int fr = 0; fr < 4; fr++) r[fr] = min(rbase + fr * 16 + lrow, n - 1);

    #pragma unroll
    for (int kk = 0; kk < 4; kk++){          // agg part (k < 128) from LDS
        short8 a[4];
        #pragma unroll
        for (int fr = 0; fr < 4; fr++)
            a[fr] = *reinterpret_cast<const short8*>(&As[fr * 16 + lrow][kk * 32 + lk]);
        #pragma unroll
        for (int cf = 0; cf < CF; cf++)
            #pragma unroll
            for (int fr = 0; fr < 4; fr++)
                acc[fr][cf] = __builtin_amdgcn_mfma_f32_16x16x32_bf16(a[fr], bfr[kk][cf], acc[fr][cf], 0, 0, 0);
    }
    #pragma unroll
    for (int kk = 4; kk < 8; kk++){          // h part (k >= 128) direct from global
        short8 a[4];
        #pragma unroll
        for (int fr = 0; fr < 4; fr++)
            a[fr] = *reinterpret_cast<const short8*>(hb + (size_t)r[fr] * D + (kk - 4) * 32 + lk);
        #pragma unroll
        for (int cf = 0; cf < CF; cf++)
            #pragma unroll
            for (int fr = 0; fr < 4; fr++)
                acc[fr][cf] = __builtin_amdgcn_mfma_f32_16x16x32_bf16(a[fr], bfr[kk][cf], acc[fr][cf], 0, 0, 0);
    }

    // ---- epilogue: bias (+relu), store
    #pragma unroll
    for (int fr = 0; fr < 4; fr++){
        int rowb = rbase + fr * 16 + (lane >> 4) * 4;
        #pragma unroll
        for (int cf = 0; cf < CF; cf++){
            int col = colbase + cf * 16 + (lane & 15);
            float bv = bias[col];
            #pragma unroll
            for (int reg = 0; reg < 4; reg++){
                int row = rowb + reg;
                if (row < n){
                    float vv = acc[fr][cf][reg] + bv;
                    if (RELU) vv = fmaxf(vv, 0.f);
                    if (OUTBF) outb[(size_t)row * DOUT + col] = f2bf(vv);
                    else       outf[(size_t)row * DOUT + col] = vv;
                }
            }
        }
    }
}

extern "C" void kernel_launch(void* const* d_in, const int* in_sizes, int n_in,
                              void* d_out, int out_size, void* d_ws, size_t ws_size,
                              hipStream_t stream)
{
    const float* x   = (const float*)d_in[0];
    const int*   ei  = (const int*)d_in[1];
    const float* Wl0 = (const float*)d_in[2];
    const float* Wr0 = (const float*)d_in[3];
    const float* b0  = (const float*)d_in[4];
    const float* Wl1 = (const float*)d_in[5];
    const float* Wr1 = (const float*)d_in[6];
    const float* b1  = (const float*)d_in[7];
    const float* Wl2 = (const float*)d_in[8];
    const float* Wr2 = (const float*)d_in[9];
    const float* b2  = (const float*)d_in[10];

    int N = in_sizes[0] / D;
    int E = in_sizes[1] / 2;
    const int* src = ei;
    const int* dst = ei + E;
    int NBK = (N + 31) >> 5;

    char* ws = (char*)d_ws;
    size_t off = 0;
    auto alloc = [&](size_t bytes) -> void* {
        void* p = ws + off;
        off = (off + bytes + 255) & ~(size_t)255;
        return p;
    };
    int*   bktcnt  = (int*)alloc((size_t)NBK * 4);
    int*   bktbase = (int*)alloc(((size_t)NBK + 1) * 4);
    int*   bktfill = (int*)alloc((size_t)NBK * 4);
    int*   roff    = (int*)alloc(((size_t)N + 1) * 4);
    int*   csr     = (int*)alloc((size_t)E * 4);
    uint2* binbuf  = (uint2*)alloc((size_t)E * 8);
    unsigned short* xb  = (unsigned short*)alloc((size_t)N * D * 2);
    unsigned short* h0  = (unsigned short*)alloc((size_t)N * D * 2);
    unsigned short* WT0 = (unsigned short*)alloc((size_t)128 * 256 * 2);
    unsigned short* WT1 = (unsigned short*)alloc((size_t)128 * 256 * 2);
    unsigned short* WT2 = (unsigned short*)alloc((size_t)64 * 256 * 2);
    unsigned short* h1  = xb;   // layer1 output overwrites xb (layer1 reads only h0)

    hipMemsetAsync(bktcnt, 0, (size_t)NBK * 4, stream);

    int n8 = N * D / 8;
    cvt_f32_bf16<<<(n8 + 255) / 256, 256, 0, stream>>>(x, xb, n8);

    count_bkt<<<(E + 255) / 256, 256, 0, stream>>>(dst, bktcnt, E);
    scan_bkt<<<1, 256, 0, stream>>>(bktcnt, bktbase, bktfill, NBK, E);
    bin_edges<<<(E + 255) / 256, 256, 0, stream>>>(src, dst, bktfill, binbuf, E);
    fill_bucket<<<NBK, 256, 0, stream>>>(binbuf, bktbase, roff, csr, N, NBK);

    wt_prep<<<(128 * 256 + 255) / 256, 256, 0, stream>>>(Wl0, Wr0, WT0, 128);
    wt_prep<<<(128 * 256 + 255) / 256, 256, 0, stream>>>(Wl1, Wr1, WT1, 128);
    wt_prep<<<(64 * 256 + 255) / 256, 256, 0, stream>>>(Wl2, Wr2, WT2, 64);

    int gL = (N + 63) / 64;
    sage_layer<128, true,  true ><<<gL, 256, 0, stream>>>(xb, roff, csr, WT0, b0, h0, nullptr, N);
    sage_layer<128, true,  true ><<<gL, 256, 0, stream>>>(h0, roff, csr, WT1, b1, h1, nullptr, N);
    sage_layer<64,  false, false><<<gL, 256, 0, stream>>>(h1, roff, csr, WT2, b2, nullptr, (float*)d_out, N);
}

// Round 3
// 396.748 us; speedup vs baseline: 1.5631x; 1.5631x over previous
//
#include <hip/hip_runtime.h>
#include <hip/hip_bf16.h>
#include <stdint.h>

#define D 128
#define BSH 9                 // bucket = 512 nodes
#define BKN 512               // nodes per bucket
#define TILE 8192             // edges per bin_edges block

typedef __attribute__((ext_vector_type(8))) short short8;
typedef __attribute__((ext_vector_type(4))) float f32x4;

__device__ inline float bf16lo(uint32_t u){ return __uint_as_float(u << 16); }
__device__ inline float bf16hi(uint32_t u){ return __uint_as_float(u & 0xffff0000u); }
__device__ inline unsigned short f2bf(float f){
    union { __hip_bfloat16 h; unsigned short u; } cvt;
    cvt.h = __float2bfloat16(f);
    return cvt.u;
}

// ---------- input fp32 -> bf16 ----------
__global__ void cvt_f32_bf16(const float* __restrict__ x, unsigned short* __restrict__ xb, int n8){
    int i = blockIdx.x * blockDim.x + threadIdx.x;
    if (i >= n8) return;
    const float4* p = reinterpret_cast<const float4*>(x) + (size_t)i * 2;
    float4 a = p[0], b = p[1];
    uint4 o;
    o.x = (uint32_t)f2bf(a.x) | ((uint32_t)f2bf(a.y) << 16);
    o.y = (uint32_t)f2bf(a.z) | ((uint32_t)f2bf(a.w) << 16);
    o.z = (uint32_t)f2bf(b.x) | ((uint32_t)f2bf(b.y) << 16);
    o.w = (uint32_t)f2bf(b.z) | ((uint32_t)f2bf(b.w) << 16);
    reinterpret_cast<uint4*>(xb)[i] = o;
}

// ---------- binned CSR build (bucket = dst >> 9) ----------
__global__ void count_bkt(const int* __restrict__ dst, int* __restrict__ cnt, int E, int nbk){
    __shared__ int h[256];
    int t = threadIdx.x;
    for (int i = t; i < nbk; i += 256) h[i] = 0;
    __syncthreads();
    for (int e = blockIdx.x * 256 + t; e < E; e += gridDim.x * 256)
        atomicAdd(&h[dst[e] >> BSH], 1);
    __syncthreads();
    for (int i = t; i < nbk; i += 256) if (h[i]) atomicAdd(&cnt[i], h[i]);
}

__global__ void scan_bkt(const int* __restrict__ cnt, int* __restrict__ base,
                         int* __restrict__ bfill, int nb, int E){
    __shared__ int s[256];
    __shared__ int carry;
    int t = threadIdx.x;
    if (t == 0) carry = 0;
    __syncthreads();
    for (int start = 0; start < nb; start += 256){
        int i = start + t;
        int v = (i < nb) ? cnt[i] : 0;
        s[t] = v;
        __syncthreads();
        for (int o = 1; o < 256; o <<= 1){
            int x = (t >= o) ? s[t - o] : 0;
            __syncthreads();
            s[t] += x;
            __syncthreads();
        }
        int excl = carry + s[t] - v;
        if (i < nb){ base[i] = excl; bfill[i] = excl; }
        __syncthreads();
        if (t == 255) carry += s[255];
        __syncthreads();
    }
    if (t == 0) base[nb] = E;
}

// LDS-staged scatter: tile -> hist -> scan -> reserve -> LDS reorder -> dense run writes
__global__ __launch_bounds__(256) void bin_edges(
    const int* __restrict__ src, const int* __restrict__ dst,
    int* __restrict__ bfill, uint32_t* __restrict__ binbuf, int E, int nbk)
{
    __shared__ int hist[256];
    __shared__ int hbase[257];
    __shared__ int gbase[256];
    __shared__ int cur[256];
    __shared__ int sc[256];
    __shared__ uint32_t stg[TILE];
    int t = threadIdx.x;
    int tile0 = blockIdx.x * TILE;
    int cnt = min(TILE, E - tile0);

    for (int i = t; i < nbk; i += 256) hist[i] = 0;
    __syncthreads();
    for (int i = t; i < cnt; i += 256)
        atomicAdd(&hist[dst[tile0 + i] >> BSH], 1);
    __syncthreads();
    int v = (t < nbk) ? hist[t] : 0;
    sc[t] = v;
    __syncthreads();
    for (int o = 1; o < 256; o <<= 1){
        int x = (t >= o) ? sc[t - o] : 0;
        __syncthreads();
        sc[t] += x;
        __syncthreads();
    }
    if (t < nbk){
        int ex = sc[t] - v;
        hbase[t] = ex; cur[t] = ex;
        gbase[t] = v ? atomicAdd(&bfill[t], v) : 0;
    }
    if (t == 0) hbase[nbk] = cnt;
    __syncthreads();
    // reorder into LDS, packing (local<<17)|src
    for (int i = t; i < cnt; i += 256){
        int d = dst[tile0 + i];
        int s_ = src[tile0 + i];
        int b = d >> BSH;
        int p = atomicAdd(&cur[b], 1);
        stg[p] = (uint32_t)s_ | ((uint32_t)(d & (BKN - 1)) << 17);
    }
    __syncthreads();
    // dense writes: slot i -> bucket via binary search over hbase
    for (int i = t; i < cnt; i += 256){
        int lo = 0, hi = nbk;
        while (hi - lo > 1){
            int mid = (lo + hi) >> 1;
            if (hbase[mid] <= i) lo = mid; else hi = mid;
        }
        binbuf[(size_t)gbase[lo] + (i - hbase[lo])] = stg[i];
    }
}

// one block per 512-node bucket: histogram -> scan -> roff + local csr scatter
__global__ __launch_bounds__(256) void fill_bucket(
    const uint32_t* __restrict__ binbuf, const int* __restrict__ bktbase,
    int* __restrict__ roff, int* __restrict__ csr, int n, int nbk)
{
    __shared__ int hist[BKN];
    __shared__ int hist2[BKN];
    __shared__ int hb2[BKN];
    __shared__ int sc[256];
    int b = blockIdx.x, t = threadIdx.x;
    int e0 = bktbase[b], e1 = bktbase[b + 1];
    int v0 = b << BSH;
    int nv = min(BKN, n - v0);

    hist[t] = 0; hist[t + 256] = 0;
    hist2[t] = 0; hist2[t + 256] = 0;
    __syncthreads();
    for (int e = e0 + t; e < e1; e += 256)
        atomicAdd(&hist[binbuf[e] >> 17], 1);
    __syncthreads();
    int a0 = hist[2 * t], a1 = hist[2 * t + 1];
    int own = a0 + a1;
    sc[t] = own;
    __syncthreads();
    for (int o = 1; o < 256; o <<= 1){
        int x = (t >= o) ? sc[t - o] : 0;
        __syncthreads();
        sc[t] += x;
        __syncthreads();
    }
    int ex = sc[t] - own;
    hb2[2 * t] = ex;
    hb2[2 * t + 1] = ex + a0;
    __syncthreads();
    for (int i = t; i < nv; i += 256) roff[v0 + i] = e0 + hb2[i];
    if (b == nbk - 1 && t == 0) roff[n] = e1;
    for (int e = e0 + t; e < e1; e += 256){
        uint32_t p = binbuf[e];
        int local = p >> 17;
        int pos = e0 + hb2[local] + atomicAdd(&hist2[local], 1);
        csr[pos] = (int)(p & 0x1FFFFu);
    }
}

// ---------- weight pre-transpose: WT[j][k] = bf16(Wcat[k][j]) ----------
__global__ void wt_prep(const float* __restrict__ Wl, const float* __restrict__ Wr,
                        unsigned short* __restrict__ WT, int dout){
    int idx = blockIdx.x * 256 + threadIdx.x;
    if (idx >= dout * 256) return;
    int k = idx & 255, j = idx >> 8;
    float w = (k < 128) ? Wl[k * dout + j] : Wr[(k - 128) * dout + j];
    WT[j * 256 + k] = f2bf(w);
}

// ---------- fused layer: aggregate(64 rows)->LDS, then [agg|h] @ [Wl;Wr] + b ----------
template<int DOUT, bool RELU, bool OUTBF>
__global__ __launch_bounds__(256, 2) void sage_layer(
    const unsigned short* __restrict__ hb,
    const int* __restrict__ roff, const int* __restrict__ csr,
    const unsigned short* __restrict__ WT, const float* __restrict__ bias,
    unsigned short* __restrict__ outb, float* __restrict__ outf, int n)
{
    constexpr int CF = DOUT / 64;
    __shared__ __align__(16) unsigned short As[64][136];
    int tid = threadIdx.x;
    int lane = tid & 63, wave = tid >> 6;
    int rbase = blockIdx.x * 64;
    int lrow = lane & 15, lk = (lane >> 4) * 8;
    int colbase = wave * 16 * CF;

    short8 bfr[8][CF];
    #pragma unroll
    for (int kk = 0; kk < 8; kk++)
        #pragma unroll
        for (int cf = 0; cf < CF; cf++)
            bfr[kk][cf] = *reinterpret_cast<const short8*>(
                WT + (size_t)(colbase + cf * 16 + lrow) * 256 + kk * 32 + lk);

    int grp = tid >> 4, li = tid & 15;
    for (int p = 0; p < 4; p++){
        int row = p * 16 + grp;
        int v = rbase + row;
        float acc[8] = {0.f,0.f,0.f,0.f,0.f,0.f,0.f,0.f};
        int dcount = 0;
        if (v < n){
            int s0 = roff[v], s1 = roff[v + 1];
            dcount = s1 - s0;
            int e = s0;
            for (; e + 1 < s1; e += 2){
                int sA = csr[e], sB = csr[e + 1];
                uint4 qa = *reinterpret_cast<const uint4*>(hb + (size_t)sA * D + li * 8);
                uint4 qb = *reinterpret_cast<const uint4*>(hb + (size_t)sB * D + li * 8);
                acc[0] += bf16lo(qa.x); acc[1] += bf16hi(qa.x);
                acc[2] += bf16lo(qa.y); acc[3] += bf16hi(qa.y);
                acc[4] += bf16lo(qa.z); acc[5] += bf16hi(qa.z);
                acc[6] += bf16lo(qa.w); acc[7] += bf16hi(qa.w);
                acc[0] += bf16lo(qb.x); acc[1] += bf16hi(qb.x);
                acc[2] += bf16lo(qb.y); acc[3] += bf16hi(qb.y);
                acc[4] += bf16lo(qb.z); acc[5] += bf16hi(qb.z);
                acc[6] += bf16lo(qb.w); acc[7] += bf16hi(qb.w);
            }
            if (e < s1){
                int sA = csr[e];
                uint4 qa = *reinterpret_cast<const uint4*>(hb + (size_t)sA * D + li * 8);
                acc[0] += bf16lo(qa.x); acc[1] += bf16hi(qa.x);
                acc[2] += bf16lo(qa.y); acc[3] += bf16hi(qa.y);
                acc[4] += bf16lo(qa.z); acc[5] += bf16hi(qa.z);
                acc[6] += bf16lo(qa.w); acc[7] += bf16hi(qa.w);
            }
        }
        float inv = (dcount > 0) ? 1.0f / (float)dcount : 0.0f;
        uint4 o;
        o.x = (uint32_t)f2bf(acc[0]*inv) | ((uint32_t)f2bf(acc[1]*inv) << 16);
        o.y = (uint32_t)f2bf(acc[2]*inv) | ((uint32_t)f2bf(acc[3]*inv) << 16);
        o.z = (uint32_t)f2bf(acc[4]*inv) | ((uint32_t)f2bf(acc[5]*inv) << 16);
        o.w = (uint32_t)f2bf(acc[6]*inv) | ((uint32_t)f2bf(acc[7]*inv) << 16);
        *reinterpret_cast<uint4*>(&As[row][li * 8]) = o;
    }
    __syncthreads();

    f32x4 acc[4][CF];
    #pragma unroll
    for (int fr = 0; fr < 4; fr++)
        #pragma unroll
        for (int cf = 0; cf < CF; cf++)
            acc[fr][cf] = (f32x4){0.f, 0.f, 0.f, 0.f};

    int r[4];
    #pragma unroll
    for (int fr = 0; fr < 4; fr++) r[fr] = min(rbase + fr * 16 + lrow, n - 1);

    #pragma unroll
    for (int kk = 0; kk < 4; kk++){
        short8 a[4];
        #pragma unroll
        for (int fr = 0; fr < 4; fr++)
            a[fr] = *reinterpret_cast<const short8*>(&As[fr * 16 + lrow][kk * 32 + lk]);
        #pragma unroll
        for (int cf = 0; cf < CF; cf++)
            #pragma unroll
            for (int fr = 0; fr < 4; fr++)
                acc[fr][cf] = __builtin_amdgcn_mfma_f32_16x16x32_bf16(a[fr], bfr[kk][cf], acc[fr][cf], 0, 0, 0);
    }
    #pragma unroll
    for (int kk = 4; kk < 8; kk++){
        short8 a[4];
        #pragma unroll
        for (int fr = 0; fr < 4; fr++)
            a[fr] = *reinterpret_cast<const short8*>(hb + (size_t)r[fr] * D + (kk - 4) * 32 + lk);
        #pragma unroll
        for (int cf = 0; cf < CF; cf++)
            #pragma unroll
            for (int fr = 0; fr < 4; fr++)
                acc[fr][cf] = __builtin_amdgcn_mfma_f32_16x16x32_bf16(a[fr], bfr[kk][cf], acc[fr][cf], 0, 0, 0);
    }

    #pragma unroll
    for (int fr = 0; fr < 4; fr++){
        int rowb = rbase + fr * 16 + (lane >> 4) * 4;
        #pragma unroll
        for (int cf = 0; cf < CF; cf++){
            int col = colbase + cf * 16 + (lane & 15);
            float bv = bias[col];
            #pragma unroll
            for (int reg = 0; reg < 4; reg++){
                int row = rowb + reg;
                if (row < n){
                    float vv = acc[fr][cf][reg] + bv;
                    if (RELU) vv = fmaxf(vv, 0.f);
                    if (OUTBF) outb[(size_t)row * DOUT + col] = f2bf(vv);
                    else       outf[(size_t)row * DOUT + col] = vv;
                }
            }
        }
    }
}

extern "C" void kernel_launch(void* const* d_in, const int* in_sizes, int n_in,
                              void* d_out, int out_size, void* d_ws, size_t ws_size,
                              hipStream_t stream)
{
    const float* x   = (const float*)d_in[0];
    const int*   ei  = (const int*)d_in[1];
    const float* Wl0 = (const float*)d_in[2];
    const float* Wr0 = (const float*)d_in[3];
    const float* b0  = (const float*)d_in[4];
    const float* Wl1 = (const float*)d_in[5];
    const float* Wr1 = (const float*)d_in[6];
    const float* b1  = (const float*)d_in[7];
    const float* Wl2 = (const float*)d_in[8];
    const float* Wr2 = (const float*)d_in[9];
    const float* b2  = (const float*)d_in[10];

    int N = in_sizes[0] / D;
    int E = in_sizes[1] / 2;
    const int* src = ei;
    const int* dst = ei + E;
    int NBK = (N + BKN - 1) >> BSH;      // 196 for N=100000

    char* ws = (char*)d_ws;
    size_t off = 0;
    auto alloc = [&](size_t bytes) -> void* {
        void* p = ws + off;
        off = (off + bytes + 255) & ~(size_t)255;
        return p;
    };
    int*      bktcnt  = (int*)alloc((size_t)NBK * 4);
    int*      bktbase = (int*)alloc(((size_t)NBK + 1) * 4);
    int*      bktfill = (int*)alloc((size_t)NBK * 4);
    int*      roff    = (int*)alloc(((size_t)N + 1) * 4);
    int*      csr     = (int*)alloc((size_t)E * 4);
    uint32_t* binbuf  = (uint32_t*)alloc((size_t)E * 4);
    unsigned short* xb  = (unsigned short*)alloc((size_t)N * D * 2);
    unsigned short* h0  = (unsigned short*)alloc((size_t)N * D * 2);
    unsigned short* WT0 = (unsigned short*)alloc((size_t)128 * 256 * 2);
    unsigned short* WT1 = (unsigned short*)alloc((size_t)128 * 256 * 2);
    unsigned short* WT2 = (unsigned short*)alloc((size_t)64 * 256 * 2);
    unsigned short* h1  = xb;   // layer1 output overwrites xb (layer1 reads only h0)

    hipMemsetAsync(bktcnt, 0, (size_t)NBK * 4, stream);

    int n8 = N * D / 8;
    cvt_f32_bf16<<<(n8 + 255) / 256, 256, 0, stream>>>(x, xb, n8);

    count_bkt<<<512, 256, 0, stream>>>(dst, bktcnt, E, NBK);
    scan_bkt<<<1, 256, 0, stream>>>(bktcnt, bktbase, bktfill, NBK, E);
    bin_edges<<<(E + TILE - 1) / TILE, 256, 0, stream>>>(src, dst, bktfill, binbuf, E, NBK);
    fill_bucket<<<NBK, 256, 0, stream>>>(binbuf, bktbase, roff, csr, N, NBK);

    wt_prep<<<(128 * 256 + 255) / 256, 256, 0, stream>>>(Wl0, Wr0, WT0, 128);
    wt_prep<<<(128 * 256 + 255) / 256, 256, 0, stream>>>(Wl1, Wr1, WT1, 128);
    wt_prep<<<(64 * 256 + 255) / 256, 256, 0, stream>>>(Wl2, Wr2, WT2, 64);

    int gL = (N + 63) / 64;
    sage_layer<128, true,  true ><<<gL, 256, 0, stream>>>(xb, roff, csr, WT0, b0, h0, nullptr, N);
    sage_layer<128, true,  true ><<<gL, 256, 0, stream>>>(h0, roff, csr, WT1, b1, h1, nullptr, N);
    sage_layer<64,  false, false><<<gL, 256, 0, stream>>>(h1, roff, csr, WT2, b2, nullptr, (float*)d_out, N);
}

// Round 4
// 378.950 us; speedup vs baseline: 1.6366x; 1.0470x over previous
//
#include <hip/hip_runtime.h>
#include <hip/hip_bf16.h>
#include <stdint.h>

#define D 128
#define BSH 9                 // bucket = 512 nodes
#define BKN 512               // nodes per bucket
#define TILE 8192             // edges per bin_edges block

typedef __attribute__((ext_vector_type(8))) short short8;
typedef __attribute__((ext_vector_type(4))) float f32x4;

__device__ inline float bf16lo(uint32_t u){ return __uint_as_float(u << 16); }
__device__ inline float bf16hi(uint32_t u){ return __uint_as_float(u & 0xffff0000u); }
__device__ inline unsigned short f2bf(float f){
    union { __hip_bfloat16 h; unsigned short u; } cvt;
    cvt.h = __float2bfloat16(f);
    return cvt.u;
}

#define ACC8(q) \
    acc[0] += bf16lo(q.x); acc[1] += bf16hi(q.x); \
    acc[2] += bf16lo(q.y); acc[3] += bf16hi(q.y); \
    acc[4] += bf16lo(q.z); acc[5] += bf16hi(q.z); \
    acc[6] += bf16lo(q.w); acc[7] += bf16hi(q.w);

// ---------- input fp32 -> bf16 ----------
__global__ void cvt_f32_bf16(const float* __restrict__ x, unsigned short* __restrict__ xb, int n8){
    int i = blockIdx.x * blockDim.x + threadIdx.x;
    if (i >= n8) return;
    const float4* p = reinterpret_cast<const float4*>(x) + (size_t)i * 2;
    float4 a = p[0], b = p[1];
    uint4 o;
    o.x = (uint32_t)f2bf(a.x) | ((uint32_t)f2bf(a.y) << 16);
    o.y = (uint32_t)f2bf(a.z) | ((uint32_t)f2bf(a.w) << 16);
    o.z = (uint32_t)f2bf(b.x) | ((uint32_t)f2bf(b.y) << 16);
    o.w = (uint32_t)f2bf(b.z) | ((uint32_t)f2bf(b.w) << 16);
    reinterpret_cast<uint4*>(xb)[i] = o;
}

// ---------- binned CSR build (bucket = dst >> 9) ----------
__global__ void count_bkt(const int* __restrict__ dst, int* __restrict__ cnt, int E, int nbk){
    __shared__ int h[256];
    int t = threadIdx.x;
    for (int i = t; i < nbk; i += 256) h[i] = 0;
    __syncthreads();
    for (int e = blockIdx.x * 256 + t; e < E; e += gridDim.x * 256)
        atomicAdd(&h[dst[e] >> BSH], 1);
    __syncthreads();
    for (int i = t; i < nbk; i += 256) if (h[i]) atomicAdd(&cnt[i], h[i]);
}

__global__ void scan_bkt(const int* __restrict__ cnt, int* __restrict__ base,
                         int* __restrict__ bfill, int nb, int E){
    __shared__ int s[256];
    __shared__ int carry;
    int t = threadIdx.x;
    if (t == 0) carry = 0;
    __syncthreads();
    for (int start = 0; start < nb; start += 256){
        int i = start + t;
        int v = (i < nb) ? cnt[i] : 0;
        s[t] = v;
        __syncthreads();
        for (int o = 1; o < 256; o <<= 1){
            int x = (t >= o) ? s[t - o] : 0;
            __syncthreads();
            s[t] += x;
            __syncthreads();
        }
        int excl = carry + s[t] - v;
        if (i < nb){ base[i] = excl; bfill[i] = excl; }
        __syncthreads();
        if (t == 255) carry += s[255];
        __syncthreads();
    }
    if (t == 0) base[nb] = E;
}

// LDS-staged scatter: tile -> hist -> scan -> reserve -> LDS reorder -> dense run writes
__global__ __launch_bounds__(256) void bin_edges(
    const int* __restrict__ src, const int* __restrict__ dst,
    int* __restrict__ bfill, uint32_t* __restrict__ binbuf, int E, int nbk)
{
    __shared__ int hist[256];
    __shared__ int hbase[257];
    __shared__ int gbase[256];
    __shared__ int cur[256];
    __shared__ int sc[256];
    __shared__ uint32_t stg[TILE];
    int t = threadIdx.x;
    int tile0 = blockIdx.x * TILE;
    int cnt = min(TILE, E - tile0);

    for (int i = t; i < nbk; i += 256) hist[i] = 0;
    __syncthreads();
    for (int i = t; i < cnt; i += 256)
        atomicAdd(&hist[dst[tile0 + i] >> BSH], 1);
    __syncthreads();
    int v = (t < nbk) ? hist[t] : 0;
    sc[t] = v;
    __syncthreads();
    for (int o = 1; o < 256; o <<= 1){
        int x = (t >= o) ? sc[t - o] : 0;
        __syncthreads();
        sc[t] += x;
        __syncthreads();
    }
    if (t < nbk){
        int ex = sc[t] - v;
        hbase[t] = ex; cur[t] = ex;
        gbase[t] = v ? atomicAdd(&bfill[t], v) : 0;
    }
    if (t == 0) hbase[nbk] = cnt;
    __syncthreads();
    for (int i = t; i < cnt; i += 256){
        int d = dst[tile0 + i];
        int s_ = src[tile0 + i];
        int b = d >> BSH;
        int p = atomicAdd(&cur[b], 1);
        stg[p] = (uint32_t)s_ | ((uint32_t)(d & (BKN - 1)) << 17);
    }
    __syncthreads();
    for (int i = t; i < cnt; i += 256){
        int lo = 0, hi = nbk;
        while (hi - lo > 1){
            int mid = (lo + hi) >> 1;
            if (hbase[mid] <= i) lo = mid; else hi = mid;
        }
        binbuf[(size_t)gbase[lo] + (i - hbase[lo])] = stg[i];
    }
}

// one block per 512-node bucket: histogram -> scan -> roff + local csr scatter
__global__ __launch_bounds__(256) void fill_bucket(
    const uint32_t* __restrict__ binbuf, const int* __restrict__ bktbase,
    int* __restrict__ roff, int* __restrict__ csr, int n, int nbk)
{
    __shared__ int hist[BKN];
    __shared__ int hist2[BKN];
    __shared__ int hb2[BKN];
    __shared__ int sc[256];
    int b = blockIdx.x, t = threadIdx.x;
    int e0 = bktbase[b], e1 = bktbase[b + 1];
    int v0 = b << BSH;
    int nv = min(BKN, n - v0);

    hist[t] = 0; hist[t + 256] = 0;
    hist2[t] = 0; hist2[t + 256] = 0;
    __syncthreads();
    for (int e = e0 + t; e < e1; e += 256)
        atomicAdd(&hist[binbuf[e] >> 17], 1);
    __syncthreads();
    int a0 = hist[2 * t], a1 = hist[2 * t + 1];
    int own = a0 + a1;
    sc[t] = own;
    __syncthreads();
    for (int o = 1; o < 256; o <<= 1){
        int x = (t >= o) ? sc[t - o] : 0;
        __syncthreads();
        sc[t] += x;
        __syncthreads();
    }
    int ex = sc[t] - own;
    hb2[2 * t] = ex;
    hb2[2 * t + 1] = ex + a0;
    __syncthreads();
    for (int i = t; i < nv; i += 256) roff[v0 + i] = e0 + hb2[i];
    if (b == nbk - 1 && t == 0) roff[n] = e1;
    for (int e = e0 + t; e < e1; e += 256){
        uint32_t p = binbuf[e];
        int local = p >> 17;
        int pos = e0 + hb2[local] + atomicAdd(&hist2[local], 1);
        csr[pos] = (int)(p & 0x1FFFFu);
    }
}

// ---------- weight pre-transpose: WT[j][k] = bf16(Wcat[k][j]) ----------
__global__ void wt_prep(const float* __restrict__ Wl, const float* __restrict__ Wr,
                        unsigned short* __restrict__ WT, int dout){
    int idx = blockIdx.x * 256 + threadIdx.x;
    if (idx >= dout * 256) return;
    int k = idx & 255, j = idx >> 8;
    float w = (k < 128) ? Wl[k * dout + j] : Wr[(k - 128) * dout + j];
    WT[j * 256 + k] = f2bf(w);
}

// ---------- fused layer: aggregate(64 rows)->LDS, then [agg|h] @ [Wl;Wr] + b ----------
template<int DOUT, bool RELU, bool OUTBF>
__global__ __launch_bounds__(256, 4) void sage_layer(
    const unsigned short* __restrict__ hb,
    const int* __restrict__ roff, const int* __restrict__ csr,
    const unsigned short* __restrict__ WT, const float* __restrict__ bias,
    unsigned short* __restrict__ outb, float* __restrict__ outf, int n)
{
    constexpr int CF = DOUT / 64;
    __shared__ __align__(16) unsigned short As[64][136];
    int tid = threadIdx.x;
    int lane = tid & 63, wave = tid >> 6;
    int rbase = blockIdx.x * 64;
    int lrow = lane & 15, lk = (lane >> 4) * 8;
    int colbase = wave * 16 * CF;

    short8 bfr[8][CF];
    #pragma unroll
    for (int kk = 0; kk < 8; kk++)
        #pragma unroll
        for (int cf = 0; cf < CF; cf++)
            bfr[kk][cf] = *reinterpret_cast<const short8*>(
                WT + (size_t)(colbase + cf * 16 + lrow) * 256 + kk * 32 + lk);

    // ---- phase 1: mean-aggregate 64 rows into LDS, 4-deep gather pipeline
    int grp = tid >> 4, li = tid & 15;
    const unsigned short* hbli = hb + li * 8;
    for (int p = 0; p < 4; p++){
        int row = p * 16 + grp;
        int v = rbase + row;
        float acc[8] = {0.f,0.f,0.f,0.f,0.f,0.f,0.f,0.f};
        int dcount = 0;
        if (v < n){
            int s0 = roff[v], s1 = roff[v + 1];
            dcount = s1 - s0;
            int e = s0;
            for (; e + 3 < s1; e += 4){
                int i0 = csr[e], i1 = csr[e + 1], i2 = csr[e + 2], i3 = csr[e + 3];
                uint4 q0 = *reinterpret_cast<const uint4*>(hbli + (size_t)i0 * D);
                uint4 q1 = *reinterpret_cast<const uint4*>(hbli + (size_t)i1 * D);
                uint4 q2 = *reinterpret_cast<const uint4*>(hbli + (size_t)i2 * D);
                uint4 q3 = *reinterpret_cast<const uint4*>(hbli + (size_t)i3 * D);
                ACC8(q0) ACC8(q1) ACC8(q2) ACC8(q3)
            }
            for (; e < s1; e++){
                int i0 = csr[e];
                uint4 q0 = *reinterpret_cast<const uint4*>(hbli + (size_t)i0 * D);
                ACC8(q0)
            }
        }
        float inv = (dcount > 0) ? 1.0f / (float)dcount : 0.0f;
        uint4 o;
        o.x = (uint32_t)f2bf(acc[0]*inv) | ((uint32_t)f2bf(acc[1]*inv) << 16);
        o.y = (uint32_t)f2bf(acc[2]*inv) | ((uint32_t)f2bf(acc[3]*inv) << 16);
        o.z = (uint32_t)f2bf(acc[4]*inv) | ((uint32_t)f2bf(acc[5]*inv) << 16);
        o.w = (uint32_t)f2bf(acc[6]*inv) | ((uint32_t)f2bf(acc[7]*inv) << 16);
        *reinterpret_cast<uint4*>(&As[row][li * 8]) = o;
    }
    __syncthreads();

    // ---- phase 2: MFMA GEMM
    f32x4 acc[4][CF];
    #pragma unroll
    for (int fr = 0; fr < 4; fr++)
        #pragma unroll
        for (int cf = 0; cf < CF; cf++)
            acc[fr][cf] = (f32x4){0.f, 0.f, 0.f, 0.f};

    int r[4];
    #pragma unroll
    for (int fr = 0; fr < 4; fr++) r[fr] = min(rbase + fr * 16 + lrow, n - 1);

    #pragma unroll
    for (int kk = 0; kk < 4; kk++){
        short8 a[4];
        #pragma unroll
        for (int fr = 0; fr < 4; fr++)
            a[fr] = *reinterpret_cast<const short8*>(&As[fr * 16 + lrow][kk * 32 + lk]);
        #pragma unroll
        for (int cf = 0; cf < CF; cf++)
            #pragma unroll
            for (int fr = 0; fr < 4; fr++)
                acc[fr][cf] = __builtin_amdgcn_mfma_f32_16x16x32_bf16(a[fr], bfr[kk][cf], acc[fr][cf], 0, 0, 0);
    }
    #pragma unroll
    for (int kk = 4; kk < 8; kk++){
        short8 a[4];
        #pragma unroll
        for (int fr = 0; fr < 4; fr++)
            a[fr] = *reinterpret_cast<const short8*>(hb + (size_t)r[fr] * D + (kk - 4) * 32 + lk);
        #pragma unroll
        for (int cf = 0; cf < CF; cf++)
            #pragma unroll
            for (int fr = 0; fr < 4; fr++)
                acc[fr][cf] = __builtin_amdgcn_mfma_f32_16x16x32_bf16(a[fr], bfr[kk][cf], acc[fr][cf], 0, 0, 0);
    }

    // ---- epilogue: bias (+relu), store
    #pragma unroll
    for (int fr = 0; fr < 4; fr++){
        int rowb = rbase + fr * 16 + (lane >> 4) * 4;
        #pragma unroll
        for (int cf = 0; cf < CF; cf++){
            int col = colbase + cf * 16 + (lane & 15);
            float bv = bias[col];
            #pragma unroll
            for (int reg = 0; reg < 4; reg++){
                int row = rowb + reg;
                if (row < n){
                    float vv = acc[fr][cf][reg] + bv;
                    if (RELU) vv = fmaxf(vv, 0.f);
                    if (OUTBF) outb[(size_t)row * DOUT + col] = f2bf(vv);
                    else       outf[(size_t)row * DOUT + col] = vv;
                }
            }
        }
    }
}

extern "C" void kernel_launch(void* const* d_in, const int* in_sizes, int n_in,
                              void* d_out, int out_size, void* d_ws, size_t ws_size,
                              hipStream_t stream)
{
    const float* x   = (const float*)d_in[0];
    const int*   ei  = (const int*)d_in[1];
    const float* Wl0 = (const float*)d_in[2];
    const float* Wr0 = (const float*)d_in[3];
    const float* b0  = (const float*)d_in[4];
    const float* Wl1 = (const float*)d_in[5];
    const float* Wr1 = (const float*)d_in[6];
    const float* b1  = (const float*)d_in[7];
    const float* Wl2 = (const float*)d_in[8];
    const float* Wr2 = (const float*)d_in[9];
    const float* b2  = (const float*)d_in[10];

    int N = in_sizes[0] / D;
    int E = in_sizes[1] / 2;
    const int* src = ei;
    const int* dst = ei + E;
    int NBK = (N + BKN - 1) >> BSH;

    char* ws = (char*)d_ws;
    size_t off = 0;
    auto alloc = [&](size_t bytes) -> void* {
        void* p = ws + off;
        off = (off + bytes + 255) & ~(size_t)255;
        return p;
    };
    int*      bktcnt  = (int*)alloc((size_t)NBK * 4);
    int*      bktbase = (int*)alloc(((size_t)NBK + 1) * 4);
    int*      bktfill = (int*)alloc((size_t)NBK * 4);
    int*      roff    = (int*)alloc(((size_t)N + 1) * 4);
    int*      csr     = (int*)alloc((size_t)E * 4);
    uint32_t* binbuf  = (uint32_t*)alloc((size_t)E * 4);
    unsigned short* xb  = (unsigned short*)alloc((size_t)N * D * 2);
    unsigned short* h0  = (unsigned short*)alloc((size_t)N * D * 2);
    unsigned short* WT0 = (unsigned short*)alloc((size_t)128 * 256 * 2);
    unsigned short* WT1 = (unsigned short*)alloc((size_t)128 * 256 * 2);
    unsigned short* WT2 = (unsigned short*)alloc((size_t)64 * 256 * 2);
    unsigned short* h1  = xb;

    hipMemsetAsync(bktcnt, 0, (size_t)NBK * 4, stream);

    int n8 = N * D / 8;
    cvt_f32_bf16<<<(n8 + 255) / 256, 256, 0, stream>>>(x, xb, n8);

    count_bkt<<<512, 256, 0, stream>>>(dst, bktcnt, E, NBK);
    scan_bkt<<<1, 256, 0, stream>>>(bktcnt, bktbase, bktfill, NBK, E);
    bin_edges<<<(E + TILE - 1) / TILE, 256, 0, stream>>>(src, dst, bktfill, binbuf, E, NBK);
    fill_bucket<<<NBK, 256, 0, stream>>>(binbuf, bktbase, roff, csr, N, NBK);

    wt_prep<<<(128 * 256 + 255) / 256, 256, 0, stream>>>(Wl0, Wr0, WT0, 128);
    wt_prep<<<(128 * 256 + 255) / 256, 256, 0, stream>>>(Wl1, Wr1, WT1, 128);
    wt_prep<<<(64 * 256 + 255) / 256, 256, 0, stream>>>(Wl2, Wr2, WT2, 64);

    int gL = (N + 63) / 64;
    sage_layer<128, true,  true ><<<gL, 256, 0, stream>>>(xb, roff, csr, WT0, b0, h0, nullptr, N);
    sage_layer<128, true,  true ><<<gL, 256, 0, stream>>>(h0, roff, csr, WT1, b1, h1, nullptr, N);
    sage_layer<64,  false, false><<<gL, 256, 0, stream>>>(h1, roff, csr, WT2, b2, nullptr, (float*)d_out, N);
}